// Round 13
// baseline (760.299 us; speedup 1.0000x reference)
//
#include <hip/hip_runtime.h>
#include <hip/hip_bf16.h>

#define NN 100000
#define EE 1600000
#define RRR 4
#define HHH 8
#define NT 400000      // RRR * NN
#define GG 782         // ceil(NT / 512) coarse buckets (seg>>9)
#define SHIFT 9
#define NBLK 512       // phase-1 blocks
#define CHUNK 3125     // EE / NBLK exactly
#define BMAX 2560      // per-bucket cap (mean 2048, sigma 45 -> 11 sigma)

typedef unsigned int u32;
typedef unsigned short u16;
typedef __attribute__((ext_vector_type(8))) short bf16x8;
typedef __attribute__((ext_vector_type(4))) float f32x4;

// ---------------- workspace layout (bytes), total ~240.5 MB (ws = 256 MiB) ----------------
static constexpr size_t OFF_KV   = 0;              // u32 [4][N][64] packed KV, ALL relations resident
static constexpr size_t OFF_Q    = 102400000;      // bf16 [4][N][64] Q
static constexpr size_t OFF_S    = 153600000;      // bf16 [4][N][64] V-sums; CSR temps alias during build
static constexpr size_t OFF_AL   = 217600000;      // f32  [4][N][8] energy sums
static constexpr size_t OFF_PW   = 230400000;      // u16  [2][17][64][64] bf16 weights, [out][c] layout
static constexpr size_t OFF_PART = 230700000;      // float2 [32][32]
static constexpr size_t OFF_FIN  = 230710000;      // float2 [32]
static constexpr size_t OFF_CW   = 230720000;      // f32 [2][4][64]
static constexpr size_t OFF_ROWP = 232400000;      // u32 [NT+1]
static constexpr size_t OFF_EDG  = 234100000;      // u32 [E]
// CSR temps alias the (dead-at-build-time) S region:
static constexpr size_t OFF_BSTORE = OFF_S;                  // u32 [E] = 6.4 MB
static constexpr size_t OFF_HIST   = OFF_S + 8000000;        // u32 [NBLK][GG] = 1.6 MB
static constexpr size_t OFF_OFFA   = OFF_S + 16000000;       // u32 [GG][NBLK] = 1.6 MB
static constexpr size_t OFF_BASE   = OFF_S + 24000000;       // u32 [GG+1]

__device__ inline u16 f2bf(float f){
  union { __hip_bfloat16 h; u16 u; } cv; cv.h = __float2bfloat16(f); return cv.u;
}
__device__ inline float bf2f(u16 u){ return __uint_as_float(((u32)u) << 16); }

// ---------------- CSR build: no-atomic two-pass partition + per-bucket counting sort ----------------
__global__ __launch_bounds__(256) void k_histA(const int* __restrict__ dst, const int* __restrict__ typ,
                                               u32* __restrict__ Hist){
  __shared__ u32 h[GG];
  int b = blockIdx.x, t = threadIdx.x;
  for (int g = t; g < GG; g += 256) h[g] = 0u;
  __syncthreads();
  int e0 = b * CHUNK;
  for (int e = e0 + t; e < e0 + CHUNK; e += 256){
    int seg = typ[e] * NN + dst[e];
    atomicAdd(&h[seg >> SHIFT], 1u);
  }
  __syncthreads();
  for (int g = t; g < GG; g += 256) Hist[(size_t)b * GG + g] = h[g];
}

__global__ __launch_bounds__(1024) void k_base(const u32* __restrict__ Hist, u32* __restrict__ Base,
                                               u32* __restrict__ rowp){
  __shared__ u32 tot[GG];
  int t = threadIdx.x;
  if (t < GG){
    u32 s = 0;
    for (int b = 0; b < NBLK; b++) s += Hist[(size_t)b * GG + t];
    tot[t] = s;
  }
  __syncthreads();
  if (t == 0){
    u32 acc = 0;
    for (int g = 0; g < GG; g++){ u32 c = tot[g]; Base[g] = acc; acc += c; }
    Base[GG] = acc;      // == EE
    rowp[NT] = EE;
  }
}

__global__ __launch_bounds__(512) void k_off(const u32* __restrict__ Hist, const u32* __restrict__ Base,
                                             u32* __restrict__ Off){
  __shared__ u32 v[NBLK];
  int g = blockIdx.x, t = threadIdx.x;     // t == phase-1 block id
  v[t] = Hist[(size_t)t * GG + g];
  __syncthreads();
  if (t == 0){
    u32 acc = Base[g];
    for (int b = 0; b < NBLK; b++){ u32 c = v[b]; v[b] = acc; acc += c; }
  }
  __syncthreads();
  Off[(size_t)g * NBLK + t] = v[t];
}

__global__ __launch_bounds__(256) void k_fill(const int* __restrict__ src, const int* __restrict__ dst,
                                              const int* __restrict__ typ, const u32* __restrict__ Off,
                                              u32* __restrict__ bstore){
  __shared__ u32 cur[GG];
  int b = blockIdx.x, t = threadIdx.x;
  for (int g = t; g < GG; g += 256) cur[g] = Off[(size_t)g * NBLK + b];
  __syncthreads();
  int e0 = b * CHUNK;
  for (int e = e0 + t; e < e0 + CHUNK; e += 256){
    int seg = typ[e] * NN + dst[e];
    u32 pos = atomicAdd(&cur[seg >> SHIFT], 1u);   // LDS atomic; exact reserved range
    bstore[pos] = ((u32)(seg & 511) << 17) | (u32)src[e];
  }
}

__global__ __launch_bounds__(256) void k_sortD(const u32* __restrict__ bstore, const u32* __restrict__ Base,
                                               u32* __restrict__ rowp, u32* __restrict__ edges){
  __shared__ u32 ent[BMAX];
  __shared__ u32 binc[512], bexc[512];
  int g = blockIdx.x, t = threadIdx.x;
  u32 base = Base[g];
  u32 cnt = Base[g + 1] - base;
  if (cnt > (u32)BMAX) cnt = (u32)BMAX;
  for (int i = t; i < 512; i += 256) binc[i] = 0u;
  __syncthreads();
  for (u32 i = t; i < cnt; i += 256){
    u32 v = bstore[base + i];
    ent[i] = v;
    atomicAdd(&binc[v >> 17], 1u);
  }
  __syncthreads();
  if (t == 0){
    u32 acc = 0;
    #pragma unroll 8
    for (int s = 0; s < 512; s++){ u32 c = binc[s]; bexc[s] = acc; binc[s] = acc; acc += c; }
  }
  __syncthreads();
  for (int s = t; s < 512; s += 256){
    int seg = g * 512 + s;
    if (seg < NT) rowp[seg] = base + bexc[s];
  }
  __syncthreads();
  for (u32 i = t; i < cnt; i += 256){
    u32 v = ent[i];
    u32 p = atomicAdd(&binc[v >> 17], 1u);
    edges[base + p] = v & 0x1FFFFu;
  }
}

// ---------------- weight repack (both layers): pwB[l][mat][out][c] bf16 ----------------
// mats 0-3 Q r0-3 ; 4-7 K ; 8-11 V ; 12 W_self ; 13-16 Wcat r0-3
__global__ __launch_bounds__(256) void k_repackbf(const float* __restrict__ WQ, const float* __restrict__ WK,
                                                  const float* __restrict__ WV, const float* __restrict__ Wcat,
                                                  const float* __restrict__ Wself, u16* __restrict__ pwB){
  int t = blockIdx.x * 256 + threadIdx.x;
  if (t >= 2 * 17 * 4096) return;
  int l = t / (17 * 4096), rem = t % (17 * 4096);
  int mat = rem >> 12, idx = rem & 4095;
  int out = idx >> 6, c = idx & 63;
  float v;
  if (mat < 12){
    int kind = mat >> 2, r = mat & 3;
    int h = out >> 3, d = out & 7;
    const float* Wsrc = (kind == 0) ? WQ : (kind == 1) ? WK : WV;
    v = Wsrc[((((l * RRR + r) * HHH + h) * 64) + c) * 8 + d];
  } else if (mat == 12){
    v = Wself[(l * 64 + c) * 64 + out];
  } else {
    int r = mat - 13;
    v = Wcat[(((l * RRR + r) * 64) + c) * 64 + out];
  }
  pwB[t] = f2bf(v);
}

// ---------------- cw[l][r][k] = sum_c Wcat[l][r][k][c] * sem_w[l][c]  (fp32) ----------------
__global__ __launch_bounds__(512) void k_cw(const float* __restrict__ Wcat, const float* __restrict__ semw,
                                            float* __restrict__ cw){
  int t = threadIdx.x;
  int l = t >> 8, r = (t >> 6) & 3, k = t & 63;
  const float* wp = Wcat + (((size_t)(l * RRR + r) * 64) + k) * 64;
  const float* sp = semw + l * 64;
  float s = 0.f;
  #pragma unroll 8
  for (int c = 0; c < 64; c++) s += wp[c] * sp[c];
  cw[t] = s;
}

// ---------------- MFMA helpers ----------------
// A-frag (16x32): row = lane&15, k = (lane>>4)*8 + j ; B-frag: col = lane&15, same k
// D (16x16): col = lane&15, row = (lane>>4)*4 + reg

// ---------------- fused Q/K/V MFMA GEMM: 12 mats, x staged once (round-11 form) ----------------
__global__ __launch_bounds__(256) void k_qkvself(const float* __restrict__ x, const u16* __restrict__ pwL,
                                                 u16* __restrict__ QAll, u32* __restrict__ kvpAll){
  __shared__ u16 xa[64][72];
  int t = threadIdx.x;
  int n0 = blockIdx.x * 64;
  { // stage x -> bf16
    int row = t >> 2, c0 = (t & 3) * 16;
    int n = n0 + row;
    float4 v0 = {}, v1 = {}, v2 = {}, v3 = {};
    if (n < NN){
      const float4* xp = (const float4*)(x + (size_t)n * 64 + c0);
      v0 = xp[0]; v1 = xp[1]; v2 = xp[2]; v3 = xp[3];
    }
    ushort4* dp = (ushort4*)&xa[row][c0];
    dp[0] = make_ushort4(f2bf(v0.x), f2bf(v0.y), f2bf(v0.z), f2bf(v0.w));
    dp[1] = make_ushort4(f2bf(v1.x), f2bf(v1.y), f2bf(v1.z), f2bf(v1.w));
    dp[2] = make_ushort4(f2bf(v2.x), f2bf(v2.y), f2bf(v2.z), f2bf(v2.w));
    dp[3] = make_ushort4(f2bf(v3.x), f2bf(v3.y), f2bf(v3.z), f2bf(v3.w));
  }
  __syncthreads();
  int w = t >> 6, lane = t & 63;
  int ra = w * 16 + (lane & 15);
  int kg = (lane >> 4) * 8;
  int cb = lane & 15;
  int rb = (lane >> 4) * 4;
  bf16x8 a0 = *(const bf16x8*)&xa[ra][kg];
  bf16x8 a1 = *(const bf16x8*)&xa[ra][32 + kg];
  f32x4 z = {0.f, 0.f, 0.f, 0.f};
  // Q (mats 0-3): B-fragments straight from global (L2-broadcast)
  #pragma unroll
  for (int m = 0; m < 4; m++){
    const u16* wp = pwL + (size_t)m * 4096;
    f32x4 acc[4] = {z, z, z, z};
    #pragma unroll
    for (int t4 = 0; t4 < 4; t4++){
      bf16x8 b0 = *(const bf16x8*)(wp + (t4 * 16 + cb) * 64 + kg);
      bf16x8 b1 = *(const bf16x8*)(wp + (t4 * 16 + cb) * 64 + 32 + kg);
      acc[t4] = __builtin_amdgcn_mfma_f32_16x16x32_bf16(a0, b0, acc[t4], 0, 0, 0);
      acc[t4] = __builtin_amdgcn_mfma_f32_16x16x32_bf16(a1, b1, acc[t4], 0, 0, 0);
    }
    u16* op = QAll + (size_t)m * NN * 64;
    #pragma unroll
    for (int t4 = 0; t4 < 4; t4++){
      #pragma unroll
      for (int i2 = 0; i2 < 4; i2++){
        int n = n0 + w * 16 + rb + i2;
        if (n < NN) op[(size_t)n * 64 + t4 * 16 + cb] = f2bf(acc[t4][i2]);
      }
    }
  }
  // K,V per relation, packed u32
  #pragma unroll
  for (int r = 0; r < 4; r++){
    const u16* wk = pwL + (size_t)(4 + r) * 4096;
    const u16* wv = pwL + (size_t)(8 + r) * 4096;
    f32x4 ak[4] = {z, z, z, z};
    f32x4 av[4] = {z, z, z, z};
    #pragma unroll
    for (int t4 = 0; t4 < 4; t4++){
      bf16x8 bk0 = *(const bf16x8*)(wk + (t4 * 16 + cb) * 64 + kg);
      bf16x8 bk1 = *(const bf16x8*)(wk + (t4 * 16 + cb) * 64 + 32 + kg);
      bf16x8 bv0 = *(const bf16x8*)(wv + (t4 * 16 + cb) * 64 + kg);
      bf16x8 bv1 = *(const bf16x8*)(wv + (t4 * 16 + cb) * 64 + 32 + kg);
      ak[t4] = __builtin_amdgcn_mfma_f32_16x16x32_bf16(a0, bk0, ak[t4], 0, 0, 0);
      ak[t4] = __builtin_amdgcn_mfma_f32_16x16x32_bf16(a1, bk1, ak[t4], 0, 0, 0);
      av[t4] = __builtin_amdgcn_mfma_f32_16x16x32_bf16(a0, bv0, av[t4], 0, 0, 0);
      av[t4] = __builtin_amdgcn_mfma_f32_16x16x32_bf16(a1, bv1, av[t4], 0, 0, 0);
    }
    u32* kp = kvpAll + (size_t)r * NN * 64;
    #pragma unroll
    for (int t4 = 0; t4 < 4; t4++){
      #pragma unroll
      for (int i2 = 0; i2 < 4; i2++){
        int n = n0 + w * 16 + rb + i2;
        if (n < NN) kp[(size_t)n * 64 + t4 * 16 + cb] = (u32)f2bf(ak[t4][i2]) | ((u32)f2bf(av[t4][i2]) << 16);
      }
    }
  }
}

// ---------------- fused edge gather: LOCKSTEP over 4 relations — 4 independent loads in flight ----------------
__global__ __launch_bounds__(256) void k_gather4(const u32* __restrict__ edges, const u32* __restrict__ rowp,
                                                 const u32* __restrict__ kvpAll, const u16* __restrict__ QAll,
                                                 u16* __restrict__ Sb, float* __restrict__ alphaB){
  int wid = threadIdx.x >> 6, lane = threadIdx.x & 63;
  int qt = lane >> 4;            // 0..3: which edge of the quad
  int i  = lane & 15;            // channel-quad index: channels 4i..4i+3 ; head = i>>1
  int n = blockIdx.x * 4 + wid;
  const float isd = 0.35355339059327373f;   // 1/sqrt(8)
  u32 beg[4], end[4], cur[4], wb[4], eidx[4];
  float q0[4], q1[4], q2[4], q3[4];
  #pragma unroll
  for (int r = 0; r < 4; r++){
    beg[r] = rowp[(size_t)r * NN + n];
    end[r] = rowp[(size_t)r * NN + n + 1];
    cur[r] = beg[r]; wb[r] = beg[r];
    eidx[r] = (beg[r] + (u32)lane < end[r]) ? edges[beg[r] + lane] : 0u;
    ushort4 qv = *(const ushort4*)&QAll[((size_t)r * NN + n) * 64 + 4 * i];
    q0[r] = bf2f(qv.x); q1[r] = bf2f(qv.y); q2[r] = bf2f(qv.z); q3[r] = bf2f(qv.w);
  }
  float sx[4] = {0.f,0.f,0.f,0.f}, sy[4] = {0.f,0.f,0.f,0.f};
  float sz[4] = {0.f,0.f,0.f,0.f}, sw[4] = {0.f,0.f,0.f,0.f};
  float aa[4] = {0.f,0.f,0.f,0.f};
  while ((cur[0] < end[0]) | (cur[1] < end[1]) | (cur[2] < end[2]) | (cur[3] < end[3])){
    u32 s[4];
    float mk[4];
    #pragma unroll
    for (int r = 0; r < 4; r++){
      if (cur[r] - wb[r] >= 64u && cur[r] < end[r]){   // slide 64-edge window
        wb[r] = cur[r];
        eidx[r] = (wb[r] + (u32)lane < end[r]) ? edges[wb[r] + lane] : 0u;
      }
      u32 wcnt = end[r] - wb[r]; if (wcnt > 64u) wcnt = 64u;
      u32 jj = cur[r] - wb[r] + (u32)qt;
      bool act = (cur[r] < end[r]) && (jj < wcnt);
      mk[r] = act ? 1.f : 0.f;
      u32 js = (jj < wcnt) ? jj : (wcnt ? wcnt - 1u : 0u);
      s[r] = (u32)__shfl((int)eidx[r], (int)js);
    }
    // 4 independent 16B gathers, issued back-to-back
    uint4 w0 = *(const uint4*)&kvpAll[(size_t)s[0] * 64 + 4 * i];
    uint4 w1 = *(const uint4*)&kvpAll[(size_t)NN * 64 + (size_t)s[1] * 64 + 4 * i];
    uint4 w2 = *(const uint4*)&kvpAll[(size_t)2 * NN * 64 + (size_t)s[2] * 64 + 4 * i];
    uint4 w3 = *(const uint4*)&kvpAll[(size_t)3 * NN * 64 + (size_t)s[3] * 64 + 4 * i];
    #pragma unroll
    for (int r = 0; r < 4; r++){
      uint4 w = (r == 0) ? w0 : (r == 1) ? w1 : (r == 2) ? w2 : w3;
      float p = q0[r] * bf2f((u16)(w.x & 0xFFFFu)) + q1[r] * bf2f((u16)(w.y & 0xFFFFu))
              + q2[r] * bf2f((u16)(w.z & 0xFFFFu)) + q3[r] * bf2f((u16)(w.w & 0xFFFFu));
      p += __shfl_xor(p, 1);               // lanes 2h,2h+1 -> full head dot
      float e = p * isd;
      e = (e > 0.f) ? e : 0.01f * e;       // leaky_relu
      aa[r] += e * mk[r];
      sx[r] += bf2f((u16)(w.x >> 16)) * mk[r];
      sy[r] += bf2f((u16)(w.y >> 16)) * mk[r];
      sz[r] += bf2f((u16)(w.z >> 16)) * mk[r];
      sw[r] += bf2f((u16)(w.w >> 16)) * mk[r];
      cur[r] += 4;
      if (cur[r] > end[r]) cur[r] = end[r];
    }
  }
  #pragma unroll
  for (int r = 0; r < 4; r++){
    // combine the 4 edge-quarters
    sx[r] += __shfl_xor(sx[r], 16); sx[r] += __shfl_xor(sx[r], 32);
    sy[r] += __shfl_xor(sy[r], 16); sy[r] += __shfl_xor(sy[r], 32);
    sz[r] += __shfl_xor(sz[r], 16); sz[r] += __shfl_xor(sz[r], 32);
    sw[r] += __shfl_xor(sw[r], 16); sw[r] += __shfl_xor(sw[r], 32);
    aa[r] += __shfl_xor(aa[r], 16); aa[r] += __shfl_xor(aa[r], 32);
    if (qt == 0){
      ushort4 o; o.x = f2bf(sx[r]); o.y = f2bf(sy[r]); o.z = f2bf(sz[r]); o.w = f2bf(sw[r]);
      *(ushort4*)&Sb[((size_t)r * NN + n) * 64 + 4 * i] = o;
      if ((i & 1) == 0) alphaB[((size_t)r * NN + n) * 8 + (i >> 1)] = aa[r];
    }
  }
}

// ---------------- column softmax stats: coalesced alpha pass ----------------
__global__ __launch_bounds__(256) void k_stats1(const float* __restrict__ alpha, float2* __restrict__ part){
  int r = blockIdx.y;
  int chunk = blockIdx.x;            // 0..31
  const int per = (NN + 31) / 32;    // 3125
  int nbeg = chunk * per;
  int nend = nbeg + per; if (nend > NN) nend = NN;
  int t = threadIdx.x;
  int h = t & 7;
  int g = t >> 3;                    // 0..31
  float m = -1e30f, s = 0.f;
  for (int n = nbeg + g; n < nend; n += 32){
    float a = alpha[((size_t)r * NN + n) * 8 + h];
    if (a > m){ s *= expf(m - a); m = a; }
    s += expf(a - m);
  }
  __shared__ float sm[256], ss[256];
  sm[t] = m; ss[t] = s; __syncthreads();
  for (int off = 128; off >= 8; off >>= 1){
    if (t < off){
      float m2 = sm[t + off], s2 = ss[t + off];
      float M = fmaxf(sm[t], m2);
      ss[t] = ss[t] * expf(sm[t] - M) + s2 * expf(m2 - M);
      sm[t] = M;
    }
    __syncthreads();
  }
  if (t < 8) part[(r * 8 + t) * 32 + chunk] = make_float2(sm[t], ss[t]);
}

__global__ void k_stats2(const float2* __restrict__ part, float2* __restrict__ fin){
  int col = threadIdx.x;
  if (col < 32){
    float M = -1e30f, S = 0.f;
    for (int i = 0; i < 32; i++){
      float2 p = part[col * 32 + i];
      float Mn = fmaxf(M, p.x);
      S = S * expf(M - Mn) + p.y * expf(p.x - Mn);
      M = Mn;
    }
    fin[col] = make_float2(M, 1.f / S);
  }
}

// ---------------- FUSED: msg GEMMs (4R) + semantic softmax + self GEMM + gelu + residual + LN ----------------
__global__ __launch_bounds__(256) void k_msgfin(const u16* __restrict__ S, const float* __restrict__ alpha,
                                                const float2* __restrict__ fin, const u16* __restrict__ pwL,
                                                const float* __restrict__ cwL, const float* __restrict__ xin,
                                                const float* __restrict__ lng, const float* __restrict__ lnb,
                                                float* __restrict__ xout){
  __shared__ u16 As[4][64][72];      // (alpha ⊙ S[r]) tiles, bf16
  __shared__ u16 xa[64][72];         // x tile, bf16 (self-GEMM A)
  __shared__ float lgs[4][64];
  __shared__ float beta[4][64];
  int t = threadIdx.x;
  int n0 = blockIdx.x * 64;
  { // stage x -> bf16
    int row = t >> 2, c0 = (t & 3) * 16;
    int n = n0 + row;
    float4 v0 = {}, v1 = {}, v2 = {}, v3 = {};
    if (n < NN){
      const float4* xp = (const float4*)(xin + (size_t)n * 64 + c0);
      v0 = xp[0]; v1 = xp[1]; v2 = xp[2]; v3 = xp[3];
    }
    ushort4* dp = (ushort4*)&xa[row][c0];
    dp[0] = make_ushort4(f2bf(v0.x), f2bf(v0.y), f2bf(v0.z), f2bf(v0.w));
    dp[1] = make_ushort4(f2bf(v1.x), f2bf(v1.y), f2bf(v1.z), f2bf(v1.w));
    dp[2] = make_ushort4(f2bf(v2.x), f2bf(v2.y), f2bf(v2.z), f2bf(v2.w));
    dp[3] = make_ushort4(f2bf(v3.x), f2bf(v3.y), f2bf(v3.z), f2bf(v3.w));
  }
  // stage (alpha ⊙ S[r]) and per-node semantic logit
  #pragma unroll
  for (int r = 0; r < 4; r++){
    int row = t >> 2, c0 = (t & 3) * 16;
    int n = n0 + row;
    int na = (n < NN) ? n : (NN - 1);
    int h0 = c0 >> 3;
    float2 f0 = fin[r * 8 + h0];
    float2 f1 = fin[r * 8 + h0 + 1];
    float a0 = alpha[((size_t)r * NN + na) * 8 + h0];
    float a1 = alpha[((size_t)r * NN + na) * 8 + h0 + 1];
    float w0 = expf(a0 - f0.x) * f0.y;
    float w1 = expf(a1 - f1.x) * f1.y;
    const u32* sp = (const u32*)(S + ((size_t)r * NN + na) * 64 + c0);
    const float* cwr = cwL + r * 64;
    float lgp = 0.f;
    #pragma unroll
    for (int jj = 0; jj < 8; jj++){
      u32 bts = sp[jj];
      float wm = (jj < 4) ? w0 : w1;
      float mv0 = bf2f((u16)(bts & 0xFFFFu)) * wm;
      float mv1 = bf2f((u16)(bts >> 16)) * wm;
      lgp += mv0 * cwr[c0 + jj * 2] + mv1 * cwr[c0 + jj * 2 + 1];
      ushort2 o;
      o.x = f2bf(mv0);
      o.y = f2bf(mv1);
      *(ushort2*)&As[r][row][c0 + jj * 2] = o;
    }
    lgp += __shfl_xor(lgp, 1);
    lgp += __shfl_xor(lgp, 2);
    if ((t & 3) == 0) lgs[r][row] = lgp;
  }
  __syncthreads();
  if (t < 64){
    float l0 = lgs[0][t], l1 = lgs[1][t], l2 = lgs[2][t], l3 = lgs[3][t];
    float mx = fmaxf(fmaxf(l0, l1), fmaxf(l2, l3));
    float e0 = expf(l0 - mx), e1 = expf(l1 - mx), e2 = expf(l2 - mx), e3 = expf(l3 - mx);
    float inv = 1.f / (e0 + e1 + e2 + e3);
    beta[0][t] = e0 * inv; beta[1][t] = e1 * inv; beta[2][t] = e2 * inv; beta[3][t] = e3 * inv;
  }
  __syncthreads();
  int w = t >> 6, lane = t & 63;
  int ra = w * 16 + (lane & 15);
  int kg = (lane >> 4) * 8;
  int cb = lane & 15;
  int rb = (lane >> 4) * 4;
  f32x4 z = {0.f, 0.f, 0.f, 0.f};
  f32x4 agg[4] = {z, z, z, z};
  // 4 relation msg-GEMMs, beta-weighted into agg
  #pragma unroll
  for (int r = 0; r < 4; r++){
    bf16x8 a0 = *(const bf16x8*)&As[r][ra][kg];
    bf16x8 a1 = *(const bf16x8*)&As[r][ra][32 + kg];
    const u16* wp = pwL + (size_t)(13 + r) * 4096;
    float br[4];
    #pragma unroll
    for (int i2 = 0; i2 < 4; i2++) br[i2] = beta[r][w * 16 + rb + i2];
    #pragma unroll
    for (int t4 = 0; t4 < 4; t4++){
      f32x4 acc = z;
      bf16x8 b0 = *(const bf16x8*)(wp + (t4 * 16 + cb) * 64 + kg);
      bf16x8 b1 = *(const bf16x8*)(wp + (t4 * 16 + cb) * 64 + 32 + kg);
      acc = __builtin_amdgcn_mfma_f32_16x16x32_bf16(a0, b0, acc, 0, 0, 0);
      acc = __builtin_amdgcn_mfma_f32_16x16x32_bf16(a1, b1, acc, 0, 0, 0);
      #pragma unroll
      for (int i2 = 0; i2 < 4; i2++) agg[t4][i2] += br[i2] * acc[i2];
    }
  }
  // self-GEMM, added unweighted
  {
    bf16x8 a0 = *(const bf16x8*)&xa[ra][kg];
    bf16x8 a1 = *(const bf16x8*)&xa[ra][32 + kg];
    const u16* wp = pwL + (size_t)12 * 4096;
    #pragma unroll
    for (int t4 = 0; t4 < 4; t4++){
      f32x4 acc = z;
      bf16x8 b0 = *(const bf16x8*)(wp + (t4 * 16 + cb) * 64 + kg);
      bf16x8 b1 = *(const bf16x8*)(wp + (t4 * 16 + cb) * 64 + 32 + kg);
      acc = __builtin_amdgcn_mfma_f32_16x16x32_bf16(a0, b0, acc, 0, 0, 0);
      acc = __builtin_amdgcn_mfma_f32_16x16x32_bf16(a1, b1, acc, 0, 0, 0);
      agg[t4] += acc;
    }
  }
  // epilogue: gelu + residual + LN (rows distributed 4/thread, 16-lane-group reduce)
  float ys[4][4];   // [t4][i2]
  #pragma unroll
  for (int t4 = 0; t4 < 4; t4++){
    #pragma unroll
    for (int i2 = 0; i2 < 4; i2++){
      int n = n0 + w * 16 + rb + i2;
      int ch = t4 * 16 + cb;
      float pre = agg[t4][i2];
      float ge = 0.5f * pre * (1.f + erff(pre * 0.70710678118654752f));
      float xv = (n < NN) ? xin[(size_t)n * 64 + ch] : 0.f;
      ys[t4][i2] = xv + ge;
    }
  }
  float mu[4], rs[4];
  #pragma unroll
  for (int i2 = 0; i2 < 4; i2++){
    float s = (ys[0][i2] + ys[1][i2]) + (ys[2][i2] + ys[3][i2]);
    s += __shfl_xor(s, 1); s += __shfl_xor(s, 2); s += __shfl_xor(s, 4); s += __shfl_xor(s, 8);
    mu[i2] = s * (1.f / 64.f);
  }
  #pragma unroll
  for (int i2 = 0; i2 < 4; i2++){
    float d0 = ys[0][i2] - mu[i2], d1 = ys[1][i2] - mu[i2];
    float d2 = ys[2][i2] - mu[i2], d3 = ys[3][i2] - mu[i2];
    float v = (d0 * d0 + d1 * d1) + (d2 * d2 + d3 * d3);
    v += __shfl_xor(v, 1); v += __shfl_xor(v, 2); v += __shfl_xor(v, 4); v += __shfl_xor(v, 8);
    rs[i2] = rsqrtf(v * (1.f / 64.f) + 1e-5f);
  }
  #pragma unroll
  for (int t4 = 0; t4 < 4; t4++){
    #pragma unroll
    for (int i2 = 0; i2 < 4; i2++){
      int n = n0 + w * 16 + rb + i2;
      int ch = t4 * 16 + cb;
      if (n < NN) xout[(size_t)n * 64 + ch] = (ys[t4][i2] - mu[i2]) * rs[i2] * lng[ch] + lnb[ch];
    }
  }
}

extern "C" void kernel_launch(void* const* d_in, const int* in_sizes, int n_in,
                              void* d_out, int out_size, void* d_ws, size_t ws_size,
                              hipStream_t stream){
  const float* x0    = (const float*)d_in[0];
  const int*   eidx  = (const int*)d_in[1];
  const int*   etyp  = (const int*)d_in[2];
  const float* WQ    = (const float*)d_in[3];
  const float* WK    = (const float*)d_in[4];
  const float* WV    = (const float*)d_in[5];
  const float* Wcat  = (const float*)d_in[6];
  const float* semw  = (const float*)d_in[7];
  const float* semb  = (const float*)d_in[8];
  const float* Wself = (const float*)d_in[9];
  const float* lng   = (const float*)d_in[10];
  const float* lnb   = (const float*)d_in[11];
  float* out = (float*)d_out;
  char* ws = (char*)d_ws;

  const int* srcArr = eidx;        // edge_index row 0 = src (j)
  const int* dstArr = eidx + EE;   // row 1 = dst (i)

  u32*  kvpAll   = (u32*)(ws + OFF_KV);
  u16*  Qb       = (u16*)(ws + OFF_Q);
  u16*  Sb       = (u16*)(ws + OFF_S);
  float* alphaB  = (float*)(ws + OFF_AL);
  u16*  pwB      = (u16*)(ws + OFF_PW);
  float2* part   = (float2*)(ws + OFF_PART);
  float2* fin    = (float2*)(ws + OFF_FIN);
  float* cw      = (float*)(ws + OFF_CW);
  u32* rowp   = (u32*)(ws + OFF_ROWP);
  u32* edges  = (u32*)(ws + OFF_EDG);
  u32* bstore = (u32*)(ws + OFF_BSTORE);   // CSR temps alias S
  u32* Hist   = (u32*)(ws + OFF_HIST);
  u32* Off    = (u32*)(ws + OFF_OFFA);
  u32* Base   = (u32*)(ws + OFF_BASE);

  // ---- CSR segmented by (relation, dst): no-atomic two-pass partition ----
  k_histA<<<NBLK, 256, 0, stream>>>(dstArr, etyp, Hist);
  k_base<<<1, 1024, 0, stream>>>(Hist, Base, rowp);
  k_off<<<GG, 512, 0, stream>>>(Hist, Base, Off);
  k_fill<<<NBLK, 256, 0, stream>>>(srcArr, dstArr, etyp, Off, bstore);
  k_sortD<<<GG, 256, 0, stream>>>(bstore, Base, rowp, edges);
  k_repackbf<<<(2 * 17 * 4096 + 255) / 256, 256, 0, stream>>>(WQ, WK, WV, Wcat, Wself, pwB);
  k_cw<<<1, 512, 0, stream>>>(Wcat, semw, cw);

  for (int l = 0; l < 2; l++){
    const float* xcur = (l == 0) ? x0 : out;
    const u16* pwL = pwB + (size_t)l * 17 * 4096;
    k_qkvself<<<1563, 256, 0, stream>>>(xcur, pwL, Qb, kvpAll);
    k_gather4<<<NN / 4, 256, 0, stream>>>(edges, rowp, kvpAll, Qb, Sb, alphaB);
    k_stats1<<<dim3(32, 4), 256, 0, stream>>>(alphaB, part);
    k_stats2<<<1, 64, 0, stream>>>(part, fin);
    k_msgfin<<<1563, 256, 0, stream>>>(Sb, alphaB, fin, pwL, cw + l * 256, xcur,
                                       lng + l * 64, lnb + l * 64, out);
  }
  (void)in_sizes; (void)n_in; (void)out_size; (void)ws_size;
  (void)semb;
}

// Round 14
// 715.825 us; speedup vs baseline: 1.0621x; 1.0621x over previous
//
#include <hip/hip_runtime.h>
#include <hip/hip_bf16.h>

#define NN 100000
#define EE 1600000
#define RRR 4
#define HHH 8
#define NT 400000      // RRR * NN
#define GG 782         // ceil(NT / 512) coarse buckets (seg>>9)
#define SHIFT 9
#define NBLK 512       // phase-1 blocks
#define CHUNK 3125     // EE / NBLK exactly
#define BMAX 2560      // per-bucket cap (mean 2048, sigma 45 -> 11 sigma)

typedef unsigned int u32;
typedef unsigned short u16;
typedef __attribute__((ext_vector_type(8))) short bf16x8;
typedef __attribute__((ext_vector_type(4))) float f32x4;

// ---------------- workspace layout (bytes), total ~240.5 MB (ws = 256 MiB) ----------------
static constexpr size_t OFF_KV   = 0;              // u32 [4][N][64] packed KV, ALL relations resident
static constexpr size_t OFF_Q    = 102400000;      // bf16 [4][N][64] Q
static constexpr size_t OFF_S    = 153600000;      // bf16 [4][N][64] V-sums; CSR temps alias during build
static constexpr size_t OFF_AL   = 217600000;      // f32  [4][N][8] energy sums
static constexpr size_t OFF_PW   = 230400000;      // u16  [2][17][64][64] bf16 weights, [out][c] layout
static constexpr size_t OFF_PART = 230700000;      // float2 [32][32]
static constexpr size_t OFF_FIN  = 230710000;      // float2 [32]
static constexpr size_t OFF_CW   = 230720000;      // f32 [2][4][64]
static constexpr size_t OFF_ROWP = 232400000;      // u32 [NT+1]
static constexpr size_t OFF_EDG  = 234100000;      // u32 [E]
// CSR temps alias the (dead-at-build-time) S region:
static constexpr size_t OFF_BSTORE = OFF_S;                  // u32 [E] = 6.4 MB
static constexpr size_t OFF_HIST   = OFF_S + 8000000;        // u32 [NBLK][GG] = 1.6 MB
static constexpr size_t OFF_OFFA   = OFF_S + 16000000;       // u32 [GG][NBLK] = 1.6 MB
static constexpr size_t OFF_BASE   = OFF_S + 24000000;       // u32 [GG+1]

__device__ inline u16 f2bf(float f){
  union { __hip_bfloat16 h; u16 u; } cv; cv.h = __float2bfloat16(f); return cv.u;
}
__device__ inline float bf2f(u16 u){ return __uint_as_float(((u32)u) << 16); }

// ---------------- CSR build: no-atomic two-pass partition + per-bucket counting sort ----------------
__global__ __launch_bounds__(256) void k_histA(const int* __restrict__ dst, const int* __restrict__ typ,
                                               u32* __restrict__ Hist){
  __shared__ u32 h[GG];
  int b = blockIdx.x, t = threadIdx.x;
  for (int g = t; g < GG; g += 256) h[g] = 0u;
  __syncthreads();
  int e0 = b * CHUNK;
  for (int e = e0 + t; e < e0 + CHUNK; e += 256){
    int seg = typ[e] * NN + dst[e];
    atomicAdd(&h[seg >> SHIFT], 1u);
  }
  __syncthreads();
  for (int g = t; g < GG; g += 256) Hist[(size_t)b * GG + g] = h[g];
}

__global__ __launch_bounds__(1024) void k_base(const u32* __restrict__ Hist, u32* __restrict__ Base,
                                               u32* __restrict__ rowp){
  __shared__ u32 tot[GG];
  int t = threadIdx.x;
  if (t < GG){
    u32 s = 0;
    for (int b = 0; b < NBLK; b++) s += Hist[(size_t)b * GG + t];
    tot[t] = s;
  }
  __syncthreads();
  if (t == 0){
    u32 acc = 0;
    for (int g = 0; g < GG; g++){ u32 c = tot[g]; Base[g] = acc; acc += c; }
    Base[GG] = acc;      // == EE
    rowp[NT] = EE;
  }
}

__global__ __launch_bounds__(512) void k_off(const u32* __restrict__ Hist, const u32* __restrict__ Base,
                                             u32* __restrict__ Off){
  __shared__ u32 v[NBLK];
  int g = blockIdx.x, t = threadIdx.x;     // t == phase-1 block id
  v[t] = Hist[(size_t)t * GG + g];
  __syncthreads();
  if (t == 0){
    u32 acc = Base[g];
    for (int b = 0; b < NBLK; b++){ u32 c = v[b]; v[b] = acc; acc += c; }
  }
  __syncthreads();
  Off[(size_t)g * NBLK + t] = v[t];
}

__global__ __launch_bounds__(256) void k_fill(const int* __restrict__ src, const int* __restrict__ dst,
                                              const int* __restrict__ typ, const u32* __restrict__ Off,
                                              u32* __restrict__ bstore){
  __shared__ u32 cur[GG];
  int b = blockIdx.x, t = threadIdx.x;
  for (int g = t; g < GG; g += 256) cur[g] = Off[(size_t)g * NBLK + b];
  __syncthreads();
  int e0 = b * CHUNK;
  for (int e = e0 + t; e < e0 + CHUNK; e += 256){
    int seg = typ[e] * NN + dst[e];
    u32 pos = atomicAdd(&cur[seg >> SHIFT], 1u);   // LDS atomic; exact reserved range
    bstore[pos] = ((u32)(seg & 511) << 17) | (u32)src[e];
  }
}

__global__ __launch_bounds__(256) void k_sortD(const u32* __restrict__ bstore, const u32* __restrict__ Base,
                                               u32* __restrict__ rowp, u32* __restrict__ edges){
  __shared__ u32 ent[BMAX];
  __shared__ u32 binc[512], bexc[512];
  int g = blockIdx.x, t = threadIdx.x;
  u32 base = Base[g];
  u32 cnt = Base[g + 1] - base;
  if (cnt > (u32)BMAX) cnt = (u32)BMAX;
  for (int i = t; i < 512; i += 256) binc[i] = 0u;
  __syncthreads();
  for (u32 i = t; i < cnt; i += 256){
    u32 v = bstore[base + i];
    ent[i] = v;
    atomicAdd(&binc[v >> 17], 1u);
  }
  __syncthreads();
  if (t == 0){
    u32 acc = 0;
    #pragma unroll 8
    for (int s = 0; s < 512; s++){ u32 c = binc[s]; bexc[s] = acc; binc[s] = acc; acc += c; }
  }
  __syncthreads();
  for (int s = t; s < 512; s += 256){
    int seg = g * 512 + s;
    if (seg < NT) rowp[seg] = base + bexc[s];
  }
  __syncthreads();
  for (u32 i = t; i < cnt; i += 256){
    u32 v = ent[i];
    u32 p = atomicAdd(&binc[v >> 17], 1u);
    edges[base + p] = v & 0x1FFFFu;
  }
}

// ---------------- weight repack (both layers): pwB[l][mat][out][c] bf16 ----------------
// mats 0-3 Q r0-3 ; 4-7 K ; 8-11 V ; 12 W_self ; 13-16 Wcat r0-3
__global__ __launch_bounds__(256) void k_repackbf(const float* __restrict__ WQ, const float* __restrict__ WK,
                                                  const float* __restrict__ WV, const float* __restrict__ Wcat,
                                                  const float* __restrict__ Wself, u16* __restrict__ pwB){
  int t = blockIdx.x * 256 + threadIdx.x;
  if (t >= 2 * 17 * 4096) return;
  int l = t / (17 * 4096), rem = t % (17 * 4096);
  int mat = rem >> 12, idx = rem & 4095;
  int out = idx >> 6, c = idx & 63;
  float v;
  if (mat < 12){
    int kind = mat >> 2, r = mat & 3;
    int h = out >> 3, d = out & 7;
    const float* Wsrc = (kind == 0) ? WQ : (kind == 1) ? WK : WV;
    v = Wsrc[((((l * RRR + r) * HHH + h) * 64) + c) * 8 + d];
  } else if (mat == 12){
    v = Wself[(l * 64 + c) * 64 + out];
  } else {
    int r = mat - 13;
    v = Wcat[(((l * RRR + r) * 64) + c) * 64 + out];
  }
  pwB[t] = f2bf(v);
}

// ---------------- cw[l][r][k] = sum_c Wcat[l][r][k][c] * sem_w[l][c]  (fp32) ----------------
__global__ __launch_bounds__(512) void k_cw(const float* __restrict__ Wcat, const float* __restrict__ semw,
                                            float* __restrict__ cw){
  int t = threadIdx.x;
  int l = t >> 8, r = (t >> 6) & 3, k = t & 63;
  const float* wp = Wcat + (((size_t)(l * RRR + r) * 64) + k) * 64;
  const float* sp = semw + l * 64;
  float s = 0.f;
  #pragma unroll 8
  for (int c = 0; c < 64; c++) s += wp[c] * sp[c];
  cw[t] = s;
}

// ---------------- MFMA helpers ----------------
// A-frag (16x32): row = lane&15, k = (lane>>4)*8 + j ; B-frag: col = lane&15, same k
// D (16x16): col = lane&15, row = (lane>>4)*4 + reg

// ---------------- fused Q/K/V MFMA GEMM: 12 mats, x staged once (round-11 form) ----------------
__global__ __launch_bounds__(256) void k_qkvself(const float* __restrict__ x, const u16* __restrict__ pwL,
                                                 u16* __restrict__ QAll, u32* __restrict__ kvpAll){
  __shared__ u16 xa[64][72];
  int t = threadIdx.x;
  int n0 = blockIdx.x * 64;
  { // stage x -> bf16
    int row = t >> 2, c0 = (t & 3) * 16;
    int n = n0 + row;
    float4 v0 = {}, v1 = {}, v2 = {}, v3 = {};
    if (n < NN){
      const float4* xp = (const float4*)(x + (size_t)n * 64 + c0);
      v0 = xp[0]; v1 = xp[1]; v2 = xp[2]; v3 = xp[3];
    }
    ushort4* dp = (ushort4*)&xa[row][c0];
    dp[0] = make_ushort4(f2bf(v0.x), f2bf(v0.y), f2bf(v0.z), f2bf(v0.w));
    dp[1] = make_ushort4(f2bf(v1.x), f2bf(v1.y), f2bf(v1.z), f2bf(v1.w));
    dp[2] = make_ushort4(f2bf(v2.x), f2bf(v2.y), f2bf(v2.z), f2bf(v2.w));
    dp[3] = make_ushort4(f2bf(v3.x), f2bf(v3.y), f2bf(v3.z), f2bf(v3.w));
  }
  __syncthreads();
  int w = t >> 6, lane = t & 63;
  int ra = w * 16 + (lane & 15);
  int kg = (lane >> 4) * 8;
  int cb = lane & 15;
  int rb = (lane >> 4) * 4;
  bf16x8 a0 = *(const bf16x8*)&xa[ra][kg];
  bf16x8 a1 = *(const bf16x8*)&xa[ra][32 + kg];
  f32x4 z = {0.f, 0.f, 0.f, 0.f};
  // Q (mats 0-3): B-fragments straight from global (L2-broadcast)
  #pragma unroll
  for (int m = 0; m < 4; m++){
    const u16* wp = pwL + (size_t)m * 4096;
    f32x4 acc[4] = {z, z, z, z};
    #pragma unroll
    for (int t4 = 0; t4 < 4; t4++){
      bf16x8 b0 = *(const bf16x8*)(wp + (t4 * 16 + cb) * 64 + kg);
      bf16x8 b1 = *(const bf16x8*)(wp + (t4 * 16 + cb) * 64 + 32 + kg);
      acc[t4] = __builtin_amdgcn_mfma_f32_16x16x32_bf16(a0, b0, acc[t4], 0, 0, 0);
      acc[t4] = __builtin_amdgcn_mfma_f32_16x16x32_bf16(a1, b1, acc[t4], 0, 0, 0);
    }
    u16* op = QAll + (size_t)m * NN * 64;
    #pragma unroll
    for (int t4 = 0; t4 < 4; t4++){
      #pragma unroll
      for (int i2 = 0; i2 < 4; i2++){
        int n = n0 + w * 16 + rb + i2;
        if (n < NN) op[(size_t)n * 64 + t4 * 16 + cb] = f2bf(acc[t4][i2]);
      }
    }
  }
  // K,V per relation, packed u32
  #pragma unroll
  for (int r = 0; r < 4; r++){
    const u16* wk = pwL + (size_t)(4 + r) * 4096;
    const u16* wv = pwL + (size_t)(8 + r) * 4096;
    f32x4 ak[4] = {z, z, z, z};
    f32x4 av[4] = {z, z, z, z};
    #pragma unroll
    for (int t4 = 0; t4 < 4; t4++){
      bf16x8 bk0 = *(const bf16x8*)(wk + (t4 * 16 + cb) * 64 + kg);
      bf16x8 bk1 = *(const bf16x8*)(wk + (t4 * 16 + cb) * 64 + 32 + kg);
      bf16x8 bv0 = *(const bf16x8*)(wv + (t4 * 16 + cb) * 64 + kg);
      bf16x8 bv1 = *(const bf16x8*)(wv + (t4 * 16 + cb) * 64 + 32 + kg);
      ak[t4] = __builtin_amdgcn_mfma_f32_16x16x32_bf16(a0, bk0, ak[t4], 0, 0, 0);
      ak[t4] = __builtin_amdgcn_mfma_f32_16x16x32_bf16(a1, bk1, ak[t4], 0, 0, 0);
      av[t4] = __builtin_amdgcn_mfma_f32_16x16x32_bf16(a0, bv0, av[t4], 0, 0, 0);
      av[t4] = __builtin_amdgcn_mfma_f32_16x16x32_bf16(a1, bv1, av[t4], 0, 0, 0);
    }
    u32* kp = kvpAll + (size_t)r * NN * 64;
    #pragma unroll
    for (int t4 = 0; t4 < 4; t4++){
      #pragma unroll
      for (int i2 = 0; i2 < 4; i2++){
        int n = n0 + w * 16 + rb + i2;
        if (n < NN) kp[(size_t)n * 64 + t4 * 16 + cb] = (u32)f2bf(ak[t4][i2]) | ((u32)f2bf(av[t4][i2]) << 16);
      }
    }
  }
}

// ---------------- fused edge gather: round-9 serial loops + hoisted 4-relation prologue ----------------
__global__ __launch_bounds__(256) void k_gather4(const u32* __restrict__ edges, const u32* __restrict__ rowp,
                                                 const u32* __restrict__ kvpAll, const u16* __restrict__ QAll,
                                                 u16* __restrict__ Sb, float* __restrict__ alphaB){
  int wid = threadIdx.x >> 6, lane = threadIdx.x & 63;
  int qt = lane >> 4;            // 0..3: which edge of the quad
  int i  = lane & 15;            // channel-quad index: channels 4i..4i+3 ; head = i>>1
  int n = blockIdx.x * 4 + wid;
  const float isd = 0.35355339059327373f;   // 1/sqrt(8)
  // ---- hoisted prologue: issue all rowp, first edge-windows, Q rows back-to-back ----
  u32 beg[4], end[4];
  #pragma unroll
  for (int r = 0; r < 4; r++){
    beg[r] = rowp[(size_t)r * NN + n];
    end[r] = rowp[(size_t)r * NN + n + 1];
  }
  u32 ew[4];
  #pragma unroll
  for (int r = 0; r < 4; r++)
    ew[r] = (beg[r] + (u32)lane < end[r]) ? edges[beg[r] + lane] : 0u;
  ushort4 qv[4];
  #pragma unroll
  for (int r = 0; r < 4; r++)
    qv[r] = *(const ushort4*)&QAll[((size_t)r * NN + n) * 64 + 4 * i];
  // ---- per-relation serial loops (round-9 inner structure, bitwise-identical accumulation) ----
  #pragma unroll
  for (int r = 0; r < 4; r++){
    const u32* kvp = kvpAll + (size_t)r * NN * 64;
    float q0 = bf2f(qv[r].x), q1 = bf2f(qv[r].y), q2 = bf2f(qv[r].z), q3 = bf2f(qv[r].w);
    float sx = 0.f, sy = 0.f, sz = 0.f, sw = 0.f, aa = 0.f;
    for (u32 base = beg[r]; base < end[r]; base += 64){
      u32 cnt = (end[r] - base < 64u) ? (end[r] - base) : 64u;
      u32 eidx = (base == beg[r]) ? ew[r]
               : ((base + (u32)lane < end[r]) ? edges[base + lane] : 0u);
      for (u32 j = 0; j < cnt; j += 4){
        u32 jj = j + (u32)qt;
        float mk = (jj < cnt) ? 1.f : 0.f;
        u32 js = (jj < cnt) ? jj : (cnt - 1);
        int s = __shfl((int)eidx, (int)js);
        uint4 w = *(const uint4*)&kvp[(size_t)s * 64 + 4 * i];
        float p = q0 * bf2f((u16)(w.x & 0xFFFFu)) + q1 * bf2f((u16)(w.y & 0xFFFFu))
                + q2 * bf2f((u16)(w.z & 0xFFFFu)) + q3 * bf2f((u16)(w.w & 0xFFFFu));
        p += __shfl_xor(p, 1);               // lanes 2h,2h+1 -> full head dot
        float e = p * isd;
        e = (e > 0.f) ? e : 0.01f * e;       // leaky_relu
        aa += e * mk;
        sx += bf2f((u16)(w.x >> 16)) * mk;
        sy += bf2f((u16)(w.y >> 16)) * mk;
        sz += bf2f((u16)(w.z >> 16)) * mk;
        sw += bf2f((u16)(w.w >> 16)) * mk;
      }
    }
    // combine the 4 edge-quarters
    sx += __shfl_xor(sx, 16); sx += __shfl_xor(sx, 32);
    sy += __shfl_xor(sy, 16); sy += __shfl_xor(sy, 32);
    sz += __shfl_xor(sz, 16); sz += __shfl_xor(sz, 32);
    sw += __shfl_xor(sw, 16); sw += __shfl_xor(sw, 32);
    aa += __shfl_xor(aa, 16); aa += __shfl_xor(aa, 32);
    if (qt == 0){
      ushort4 o; o.x = f2bf(sx); o.y = f2bf(sy); o.z = f2bf(sz); o.w = f2bf(sw);
      *(ushort4*)&Sb[((size_t)r * NN + n) * 64 + 4 * i] = o;
      if ((i & 1) == 0) alphaB[((size_t)r * NN + n) * 8 + (i >> 1)] = aa;
    }
  }
}

// ---------------- column softmax stats: coalesced alpha pass ----------------
__global__ __launch_bounds__(256) void k_stats1(const float* __restrict__ alpha, float2* __restrict__ part){
  int r = blockIdx.y;
  int chunk = blockIdx.x;            // 0..31
  const int per = (NN + 31) / 32;    // 3125
  int nbeg = chunk * per;
  int nend = nbeg + per; if (nend > NN) nend = NN;
  int t = threadIdx.x;
  int h = t & 7;
  int g = t >> 3;                    // 0..31
  float m = -1e30f, s = 0.f;
  for (int n = nbeg + g; n < nend; n += 32){
    float a = alpha[((size_t)r * NN + n) * 8 + h];
    if (a > m){ s *= expf(m - a); m = a; }
    s += expf(a - m);
  }
  __shared__ float sm[256], ss[256];
  sm[t] = m; ss[t] = s; __syncthreads();
  for (int off = 128; off >= 8; off >>= 1){
    if (t < off){
      float m2 = sm[t + off], s2 = ss[t + off];
      float M = fmaxf(sm[t], m2);
      ss[t] = ss[t] * expf(sm[t] - M) + s2 * expf(m2 - M);
      sm[t] = M;
    }
    __syncthreads();
  }
  if (t < 8) part[(r * 8 + t) * 32 + chunk] = make_float2(sm[t], ss[t]);
}

__global__ void k_stats2(const float2* __restrict__ part, float2* __restrict__ fin){
  int col = threadIdx.x;
  if (col < 32){
    float M = -1e30f, S = 0.f;
    for (int i = 0; i < 32; i++){
      float2 p = part[col * 32 + i];
      float Mn = fmaxf(M, p.x);
      S = S * expf(M - Mn) + p.y * expf(p.x - Mn);
      M = Mn;
    }
    fin[col] = make_float2(M, 1.f / S);
  }
}

// ---------------- FUSED: msg GEMMs (4R) + semantic softmax + self GEMM + gelu + residual + LN ----------------
__global__ __launch_bounds__(256) void k_msgfin(const u16* __restrict__ S, const float* __restrict__ alpha,
                                                const float2* __restrict__ fin, const u16* __restrict__ pwL,
                                                const float* __restrict__ cwL, const float* __restrict__ xin,
                                                const float* __restrict__ lng, const float* __restrict__ lnb,
                                                float* __restrict__ xout){
  __shared__ u16 As[4][64][72];      // (alpha ⊙ S[r]) tiles, bf16
  __shared__ u16 xa[64][72];         // x tile, bf16 (self-GEMM A)
  __shared__ float lgs[4][64];
  __shared__ float beta[4][64];
  int t = threadIdx.x;
  int n0 = blockIdx.x * 64;
  { // stage x -> bf16
    int row = t >> 2, c0 = (t & 3) * 16;
    int n = n0 + row;
    float4 v0 = {}, v1 = {}, v2 = {}, v3 = {};
    if (n < NN){
      const float4* xp = (const float4*)(xin + (size_t)n * 64 + c0);
      v0 = xp[0]; v1 = xp[1]; v2 = xp[2]; v3 = xp[3];
    }
    ushort4* dp = (ushort4*)&xa[row][c0];
    dp[0] = make_ushort4(f2bf(v0.x), f2bf(v0.y), f2bf(v0.z), f2bf(v0.w));
    dp[1] = make_ushort4(f2bf(v1.x), f2bf(v1.y), f2bf(v1.z), f2bf(v1.w));
    dp[2] = make_ushort4(f2bf(v2.x), f2bf(v2.y), f2bf(v2.z), f2bf(v2.w));
    dp[3] = make_ushort4(f2bf(v3.x), f2bf(v3.y), f2bf(v3.z), f2bf(v3.w));
  }
  // stage (alpha ⊙ S[r]) and per-node semantic logit
  #pragma unroll
  for (int r = 0; r < 4; r++){
    int row = t >> 2, c0 = (t & 3) * 16;
    int n = n0 + row;
    int na = (n < NN) ? n : (NN - 1);
    int h0 = c0 >> 3;
    float2 f0 = fin[r * 8 + h0];
    float2 f1 = fin[r * 8 + h0 + 1];
    float a0 = alpha[((size_t)r * NN + na) * 8 + h0];
    float a1 = alpha[((size_t)r * NN + na) * 8 + h0 + 1];
    float w0 = expf(a0 - f0.x) * f0.y;
    float w1 = expf(a1 - f1.x) * f1.y;
    const u32* sp = (const u32*)(S + ((size_t)r * NN + na) * 64 + c0);
    const float* cwr = cwL + r * 64;
    float lgp = 0.f;
    #pragma unroll
    for (int jj = 0; jj < 8; jj++){
      u32 bts = sp[jj];
      float wm = (jj < 4) ? w0 : w1;
      float mv0 = bf2f((u16)(bts & 0xFFFFu)) * wm;
      float mv1 = bf2f((u16)(bts >> 16)) * wm;
      lgp += mv0 * cwr[c0 + jj * 2] + mv1 * cwr[c0 + jj * 2 + 1];
      ushort2 o;
      o.x = f2bf(mv0);
      o.y = f2bf(mv1);
      *(ushort2*)&As[r][row][c0 + jj * 2] = o;
    }
    lgp += __shfl_xor(lgp, 1);
    lgp += __shfl_xor(lgp, 2);
    if ((t & 3) == 0) lgs[r][row] = lgp;
  }
  __syncthreads();
  if (t < 64){
    float l0 = lgs[0][t], l1 = lgs[1][t], l2 = lgs[2][t], l3 = lgs[3][t];
    float mx = fmaxf(fmaxf(l0, l1), fmaxf(l2, l3));
    float e0 = expf(l0 - mx), e1 = expf(l1 - mx), e2 = expf(l2 - mx), e3 = expf(l3 - mx);
    float inv = 1.f / (e0 + e1 + e2 + e3);
    beta[0][t] = e0 * inv; beta[1][t] = e1 * inv; beta[2][t] = e2 * inv; beta[3][t] = e3 * inv;
  }
  __syncthreads();
  int w = t >> 6, lane = t & 63;
  int ra = w * 16 + (lane & 15);
  int kg = (lane >> 4) * 8;
  int cb = lane & 15;
  int rb = (lane >> 4) * 4;
  f32x4 z = {0.f, 0.f, 0.f, 0.f};
  f32x4 agg[4] = {z, z, z, z};
  // 4 relation msg-GEMMs, beta-weighted into agg
  #pragma unroll
  for (int r = 0; r < 4; r++){
    bf16x8 a0 = *(const bf16x8*)&As[r][ra][kg];
    bf16x8 a1 = *(const bf16x8*)&As[r][ra][32 + kg];
    const u16* wp = pwL + (size_t)(13 + r) * 4096;
    float br[4];
    #pragma unroll
    for (int i2 = 0; i2 < 4; i2++) br[i2] = beta[r][w * 16 + rb + i2];
    #pragma unroll
    for (int t4 = 0; t4 < 4; t4++){
      f32x4 acc = z;
      bf16x8 b0 = *(const bf16x8*)(wp + (t4 * 16 + cb) * 64 + kg);
      bf16x8 b1 = *(const bf16x8*)(wp + (t4 * 16 + cb) * 64 + 32 + kg);
      acc = __builtin_amdgcn_mfma_f32_16x16x32_bf16(a0, b0, acc, 0, 0, 0);
      acc = __builtin_amdgcn_mfma_f32_16x16x32_bf16(a1, b1, acc, 0, 0, 0);
      #pragma unroll
      for (int i2 = 0; i2 < 4; i2++) agg[t4][i2] += br[i2] * acc[i2];
    }
  }
  // self-GEMM, added unweighted
  {
    bf16x8 a0 = *(const bf16x8*)&xa[ra][kg];
    bf16x8 a1 = *(const bf16x8*)&xa[ra][32 + kg];
    const u16* wp = pwL + (size_t)12 * 4096;
    #pragma unroll
    for (int t4 = 0; t4 < 4; t4++){
      f32x4 acc = z;
      bf16x8 b0 = *(const bf16x8*)(wp + (t4 * 16 + cb) * 64 + kg);
      bf16x8 b1 = *(const bf16x8*)(wp + (t4 * 16 + cb) * 64 + 32 + kg);
      acc = __builtin_amdgcn_mfma_f32_16x16x32_bf16(a0, b0, acc, 0, 0, 0);
      acc = __builtin_amdgcn_mfma_f32_16x16x32_bf16(a1, b1, acc, 0, 0, 0);
      agg[t4] += acc;
    }
  }
  // epilogue: gelu + residual + LN (rows distributed 4/thread, 16-lane-group reduce)
  float ys[4][4];   // [t4][i2]
  #pragma unroll
  for (int t4 = 0; t4 < 4; t4++){
    #pragma unroll
    for (int i2 = 0; i2 < 4; i2++){
      int n = n0 + w * 16 + rb + i2;
      int ch = t4 * 16 + cb;
      float pre = agg[t4][i2];
      float ge = 0.5f * pre * (1.f + erff(pre * 0.70710678118654752f));
      float xv = (n < NN) ? xin[(size_t)n * 64 + ch] : 0.f;
      ys[t4][i2] = xv + ge;
    }
  }
  float mu[4], rs[4];
  #pragma unroll
  for (int i2 = 0; i2 < 4; i2++){
    float s = (ys[0][i2] + ys[1][i2]) + (ys[2][i2] + ys[3][i2]);
    s += __shfl_xor(s, 1); s += __shfl_xor(s, 2); s += __shfl_xor(s, 4); s += __shfl_xor(s, 8);
    mu[i2] = s * (1.f / 64.f);
  }
  #pragma unroll
  for (int i2 = 0; i2 < 4; i2++){
    float d0 = ys[0][i2] - mu[i2], d1 = ys[1][i2] - mu[i2];
    float d2 = ys[2][i2] - mu[i2], d3 = ys[3][i2] - mu[i2];
    float v = (d0 * d0 + d1 * d1) + (d2 * d2 + d3 * d3);
    v += __shfl_xor(v, 1); v += __shfl_xor(v, 2); v += __shfl_xor(v, 4); v += __shfl_xor(v, 8);
    rs[i2] = rsqrtf(v * (1.f / 64.f) + 1e-5f);
  }
  #pragma unroll
  for (int t4 = 0; t4 < 4; t4++){
    #pragma unroll
    for (int i2 = 0; i2 < 4; i2++){
      int n = n0 + w * 16 + rb + i2;
      int ch = t4 * 16 + cb;
      if (n < NN) xout[(size_t)n * 64 + ch] = (ys[t4][i2] - mu[i2]) * rs[i2] * lng[ch] + lnb[ch];
    }
  }
}

extern "C" void kernel_launch(void* const* d_in, const int* in_sizes, int n_in,
                              void* d_out, int out_size, void* d_ws, size_t ws_size,
                              hipStream_t stream){
  const float* x0    = (const float*)d_in[0];
  const int*   eidx  = (const int*)d_in[1];
  const int*   etyp  = (const int*)d_in[2];
  const float* WQ    = (const float*)d_in[3];
  const float* WK    = (const float*)d_in[4];
  const float* WV    = (const float*)d_in[5];
  const float* Wcat  = (const float*)d_in[6];
  const float* semw  = (const float*)d_in[7];
  const float* semb  = (const float*)d_in[8];
  const float* Wself = (const float*)d_in[9];
  const float* lng   = (const float*)d_in[10];
  const float* lnb   = (const float*)d_in[11];
  float* out = (float*)d_out;
  char* ws = (char*)d_ws;

  const int* srcArr = eidx;        // edge_index row 0 = src (j)
  const int* dstArr = eidx + EE;   // row 1 = dst (i)

  u32*  kvpAll   = (u32*)(ws + OFF_KV);
  u16*  Qb       = (u16*)(ws + OFF_Q);
  u16*  Sb       = (u16*)(ws + OFF_S);
  float* alphaB  = (float*)(ws + OFF_AL);
  u16*  pwB      = (u16*)(ws + OFF_PW);
  float2* part   = (float2*)(ws + OFF_PART);
  float2* fin    = (float2*)(ws + OFF_FIN);
  float* cw      = (float*)(ws + OFF_CW);
  u32* rowp   = (u32*)(ws + OFF_ROWP);
  u32* edges  = (u32*)(ws + OFF_EDG);
  u32* bstore = (u32*)(ws + OFF_BSTORE);   // CSR temps alias S
  u32* Hist   = (u32*)(ws + OFF_HIST);
  u32* Off    = (u32*)(ws + OFF_OFFA);
  u32* Base   = (u32*)(ws + OFF_BASE);

  // ---- CSR segmented by (relation, dst): no-atomic two-pass partition ----
  k_histA<<<NBLK, 256, 0, stream>>>(dstArr, etyp, Hist);
  k_base<<<1, 1024, 0, stream>>>(Hist, Base, rowp);
  k_off<<<GG, 512, 0, stream>>>(Hist, Base, Off);
  k_fill<<<NBLK, 256, 0, stream>>>(srcArr, dstArr, etyp, Off, bstore);
  k_sortD<<<GG, 256, 0, stream>>>(bstore, Base, rowp, edges);
  k_repackbf<<<(2 * 17 * 4096 + 255) / 256, 256, 0, stream>>>(WQ, WK, WV, Wcat, Wself, pwB);
  k_cw<<<1, 512, 0, stream>>>(Wcat, semw, cw);

  for (int l = 0; l < 2; l++){
    const float* xcur = (l == 0) ? x0 : out;
    const u16* pwL = pwB + (size_t)l * 17 * 4096;
    k_qkvself<<<1563, 256, 0, stream>>>(xcur, pwL, Qb, kvpAll);
    k_gather4<<<NN / 4, 256, 0, stream>>>(edges, rowp, kvpAll, Qb, Sb, alphaB);
    k_stats1<<<dim3(32, 4), 256, 0, stream>>>(alphaB, part);
    k_stats2<<<1, 64, 0, stream>>>(part, fin);
    k_msgfin<<<1563, 256, 0, stream>>>(Sb, alphaB, fin, pwL, cw + l * 256, xcur,
                                       lng + l * 64, lnb + l * 64, out);
  }
  (void)in_sizes; (void)n_in; (void)out_size; (void)ws_size;
  (void)semb;
}